// Round 14
// baseline (712.094 us; speedup 1.0000x reference)
//
#include <hip/hip_runtime.h>

#define BS 16
#define CI 2048
#define NI 16
#define CO 64
#define NO 32
#define KK 2048   // CO*NO
#define NGRP 256  // i-groups

__device__ __forceinline__ void load_lds16(const float* g, float* l) {
    __builtin_amdgcn_global_load_lds(
        (const __attribute__((address_space(1))) void*)g,
        (__attribute__((address_space(3))) void*)l, 16, 0, 0);
}

#define WAITVM10 asm volatile("s_waitcnt vmcnt(10)" ::: "memory")
#define WAITVM2  asm volatile("s_waitcnt vmcnt(2)" ::: "memory")
#define WAITVM0  asm volatile("s_waitcnt vmcnt(0)" ::: "memory")
#define WAITLGKM asm volatile("s_waitcnt lgkmcnt(0)" ::: "memory")
#define BAR __builtin_amdgcn_s_barrier
#define MEMFENCE asm volatile("" ::: "memory")

__device__ __forceinline__ unsigned bf16rne(float f) {
    unsigned u = __float_as_uint(f);
    return (u + 0x7fffu + ((u >> 16) & 1u)) >> 16;
}
__device__ __forceinline__ unsigned pack2(float lo, float hi) {
    return bf16rne(lo) | (bf16rne(hi) << 16);
}
__device__ __forceinline__ float bflo(unsigned u) { return __uint_as_float(u << 16); }
__device__ __forceinline__ float bfhi(unsigned u) { return __uint_as_float(u & 0xffff0000u); }

// ---------------- pass 0: weights -> votes(bf16) ---------------------------
// 512 thr, 512 blocks (sibling pairs share weights via same-XCD L2).
// NO acc/partials (uniform sum moved to vote_sum): live set ~55 VGPR;
// __launch_bounds__(512, 8) pins a 64-VGPR budget -> 4 blocks/CU (LDS 37 KB),
// 32 waves/CU. Self-sliced staging: thread t writes+reads wbuf[*][4t..4t+3]
// only -> no barriers; counted own-wave vmcnt ledger (r12 pattern transposed
// to 2-load subtiles: steady vm(2); post-store boundary vm(10); stores get 2
// compute-rounds of cover before the q2 forced drain).
__global__ __launch_bounds__(512, 8) void votes_kernel(
    const float* __restrict__ x,      // [BS][CI][NI]
    const float* __restrict__ w,      // [CI][NI][KK]
    unsigned* __restrict__ votes)     // [CI][BS][KK/2] u32 = 2 bf16
{
    __shared__ float wbuf[2][2 * KK]; // 32 KB: double-buffered 2-row subtiles
    __shared__ float xb[8][8][NI];    // 4 KB

    const int t = threadIdx.x;
    const int phys = blockIdx.x;
    const int xcd = phys & 7;
    const int slot = phys >> 3;
    const int pairid = xcd * 32 + (slot >> 1);
    const int half = slot & 1;
    const int k4 = 4 * t;

    {
        int il = t >> 6, b = (t >> 3) & 7, n0 = (t & 7) * 2;
        int i = pairid + il * NGRP;
        *(float2*)&xb[il][b][n0] =
            *(const float2*)&x[((size_t)(half * 8 + b) * CI + i) * NI + n0];
    }
    __syncthreads();  // x visible; counters drained: exact ledger starts

    auto issue = [&](int s) {   // subtile s: capsule s>>3, ni rows 2(s&7), +1
        int ilp = s >> 3, qp = s & 7;
        const float* gb = w + ((size_t)(pairid + ilp * NGRP) * NI + 2 * qp) * KK + k4;
        float* lb = wbuf[s & 1] + k4;
        load_lds16(gb, lb);
        load_lds16(gb + KK, lb + KK);
    };

    issue(0); issue(1);

#pragma unroll 1
    for (int il = 0; il < 8; ++il) {
        float4 v[8];
#pragma unroll
        for (int b = 0; b < 8; ++b) v[b] = make_float4(0.f, 0.f, 0.f, 0.f);

#pragma unroll
        for (int q = 0; q < 8; ++q) {
            const int s = il * 8 + q;
            if (s == 63) { WAITVM0; }
            else if (il > 0 && q < 2) { WAITVM10; }  // 8 stores + next subtile out
            else { WAITVM2; }                        // next subtile (2 loads) out
            {
                float4 wA = *(const float4*)&wbuf[q & 1][k4];
                float4 wB = *(const float4*)&wbuf[q & 1][KK + k4];
#pragma unroll
                for (int b = 0; b < 8; ++b) {
                    float2 xv = *(const float2*)&xb[il][b][2 * q];
                    v[b].x = fmaf(xv.x, wA.x, v[b].x);
                    v[b].y = fmaf(xv.x, wA.y, v[b].y);
                    v[b].z = fmaf(xv.x, wA.z, v[b].z);
                    v[b].w = fmaf(xv.x, wA.w, v[b].w);
                    v[b].x = fmaf(xv.y, wB.x, v[b].x);
                    v[b].y = fmaf(xv.y, wB.y, v[b].y);
                    v[b].z = fmaf(xv.y, wB.z, v[b].z);
                    v[b].w = fmaf(xv.y, wB.w, v[b].w);
                }
            }
            WAITLGKM;   // my LDS reads retired before buffer reuse
            if (s + 2 < 64) issue(s + 2);
        }

        // pack/store bf16 votes (8 x 8B stores, fenced into the ledger)
        const size_t vbase = ((size_t)(pairid + il * NGRP) * BS + half * 8) * (KK / 2) + 2 * t;
#pragma unroll
        for (int b = 0; b < 8; ++b) {
            uint2 pk;
            pk.x = pack2(v[b].x, v[b].y);
            pk.y = pack2(v[b].z, v[b].w);
            *(uint2*)&votes[vbase + (size_t)b * (KK / 2)] = pk;
        }
        MEMFENCE;
    }
}

// ---------------- uniform sum: votes -> part1[32][BS][KK] ------------------
// 512 blocks x 256 thr: block = (ic = blk>>4: 64 i's, b = blk&15).
// Thread owns a uint4 column (8 k); 4-deep unrolled i-loop for in-flight BW.
__global__ __launch_bounds__(256) void vote_sum(
    const unsigned* __restrict__ votes, float* __restrict__ part1)
{
    const int t = threadIdx.x;
    const int b = blockIdx.x & 15;
    const int ic = blockIdx.x >> 4;   // 0..31
    float s[8];
#pragma unroll
    for (int j = 0; j < 8; ++j) s[j] = 0.f;
    const unsigned* base = votes + (size_t)b * (KK / 2) + 4 * t;
    const size_t istride = (size_t)BS * (KK / 2);
#pragma unroll 1
    for (int i0 = ic * 64; i0 < ic * 64 + 64; i0 += 4) {
        uint4 u0 = *(const uint4*)(base + (size_t)(i0 + 0) * istride);
        uint4 u1 = *(const uint4*)(base + (size_t)(i0 + 1) * istride);
        uint4 u2 = *(const uint4*)(base + (size_t)(i0 + 2) * istride);
        uint4 u3 = *(const uint4*)(base + (size_t)(i0 + 3) * istride);
        s[0] += bflo(u0.x) + bflo(u1.x) + bflo(u2.x) + bflo(u3.x);
        s[1] += bfhi(u0.x) + bfhi(u1.x) + bfhi(u2.x) + bfhi(u3.x);
        s[2] += bflo(u0.y) + bflo(u1.y) + bflo(u2.y) + bflo(u3.y);
        s[3] += bfhi(u0.y) + bfhi(u1.y) + bfhi(u2.y) + bfhi(u3.y);
        s[4] += bflo(u0.z) + bflo(u1.z) + bflo(u2.z) + bflo(u3.z);
        s[5] += bfhi(u0.z) + bfhi(u1.z) + bfhi(u2.z) + bfhi(u3.z);
        s[6] += bflo(u0.w) + bflo(u1.w) + bflo(u2.w) + bflo(u3.w);
        s[7] += bfhi(u0.w) + bfhi(u1.w) + bfhi(u2.w) + bfhi(u3.w);
    }
    float* op = part1 + ((size_t)ic * BS + b) * KK + 8 * t;
    *(float4*)op = make_float4(s[0], s[1], s[2], s[3]);
    *(float4*)(op + 4) = make_float4(s[4], s[5], s[6], s[7]);
}

// ---------------- routing from bf16 votes (r13 structure, no logits) -------
// Linearity: iter-3 logits = v.act1 + v.act2 = v.(act1+act2), so route2 is
// route1 with actb = act1+act2. No logits traffic at all.
#define RILBODY(IL, VC, VN)                                                    \
  {                                                                            \
    const int buf = (IL) & 1;                                                  \
    if ((IL) < 7) {                                                            \
      _Pragma("unroll")                                                        \
      for (int lb = 0; lb < 2; ++lb)                                           \
        VN[lb] = *(const uint4*)&votes[((size_t)(gid + ((IL) + 1) * NGRP) * BS \
                                        + bg0 + lb) * (KK / 2) + 4 * ks];      \
    }                                                                          \
    float dv[2];                                                               \
    _Pragma("unroll")                                                          \
    for (int lb = 0; lb < 2; ++lb) {                                           \
      float4 a0 = *(const float4*)&actb[2 * bh + lb][k8];                      \
      float4 a1 = *(const float4*)&actb[2 * bh + lb][k8 + 4];                  \
      float d = bflo(VC[lb].x) * a0.x + bfhi(VC[lb].x) * a0.y                  \
              + bflo(VC[lb].y) * a0.z + bfhi(VC[lb].y) * a0.w                  \
              + bflo(VC[lb].z) * a1.x + bfhi(VC[lb].z) * a1.y                  \
              + bflo(VC[lb].w) * a1.z + bfhi(VC[lb].w) * a1.w;                 \
      d += __shfl_xor(d, 1, 4);                                                \
      d += __shfl_xor(d, 2, 4);                                                \
      dv[lb] = d;                                                              \
    }                                                                          \
    if (j4 == 0) sm[buf][(2 * bh) * 65 + co] = dv[0];                          \
    if (j4 == 1) sm[buf][(2 * bh + 1) * 65 + co] = dv[1];                      \
    WAITLGKM; BAR();                                                           \
    if (t < 256) {                                                             \
      float l0 = sm[buf][(t >> 6) * 65 + (t & 63)];                            \
      float mx = l0;                                                           \
      mx = fmaxf(mx, __shfl_xor(mx, 1, 64));                                   \
      mx = fmaxf(mx, __shfl_xor(mx, 2, 64));                                   \
      mx = fmaxf(mx, __shfl_xor(mx, 4, 64));                                   \
      mx = fmaxf(mx, __shfl_xor(mx, 8, 64));                                   \
      mx = fmaxf(mx, __shfl_xor(mx, 16, 64));                                  \
      mx = fmaxf(mx, __shfl_xor(mx, 32, 64));                                  \
      float e = __expf(l0 - mx);                                               \
      float ssum = e;                                                          \
      ssum += __shfl_xor(ssum, 1, 64);                                         \
      ssum += __shfl_xor(ssum, 2, 64);                                         \
      ssum += __shfl_xor(ssum, 4, 64);                                         \
      ssum += __shfl_xor(ssum, 8, 64);                                         \
      ssum += __shfl_xor(ssum, 16, 64);                                        \
      ssum += __shfl_xor(ssum, 32, 64);                                        \
      sm[buf][(t >> 6) * 65 + (t & 63)] = e / ssum;                            \
      WAITLGKM;                                                                \
    }                                                                          \
    BAR();                                                                     \
    _Pragma("unroll")                                                          \
    for (int lb = 0; lb < 2; ++lb) {                                           \
      float r = sm[buf][(2 * bh + lb) * 65 + co];                              \
      acc[2 * lb + 0].x = fmaf(r, bflo(VC[lb].x), acc[2 * lb + 0].x);          \
      acc[2 * lb + 0].y = fmaf(r, bfhi(VC[lb].x), acc[2 * lb + 0].y);          \
      acc[2 * lb + 0].z = fmaf(r, bflo(VC[lb].y), acc[2 * lb + 0].z);          \
      acc[2 * lb + 0].w = fmaf(r, bfhi(VC[lb].y), acc[2 * lb + 0].w);          \
      acc[2 * lb + 1].x = fmaf(r, bflo(VC[lb].z), acc[2 * lb + 1].x);          \
      acc[2 * lb + 1].y = fmaf(r, bfhi(VC[lb].z), acc[2 * lb + 1].y);          \
      acc[2 * lb + 1].z = fmaf(r, bflo(VC[lb].w), acc[2 * lb + 1].z);          \
      acc[2 * lb + 1].w = fmaf(r, bfhi(VC[lb].w), acc[2 * lb + 1].w);          \
    }                                                                          \
  }

template <bool TWOACT>
__global__ __launch_bounds__(512, 2) void route_kernel(
    const unsigned* __restrict__ votes,   // [CI][BS][KK/2]
    const float* __restrict__ act1,       // [BS][KK]
    const float* __restrict__ act2,       // [BS][KK] (TWOACT only)
    float* __restrict__ partials)         // [NGRP][BS][KK]
{
    __shared__ float actb[4][KK];   // 32 KB (act1 or act1+act2)
    __shared__ float sm[2][4 * 65]; // 2 KB, double-buffered per il

    const int t = threadIdx.x;       // 0..511
    const int phys = blockIdx.x;     // 0..1023
    const int xcd = phys & 7;
    const int slot = phys >> 3;      // 0..127
    const int gid = xcd * 32 + (slot >> 2);  // 0..255
    const int quarter = slot & 3;    // batches quarter*4 .. +3

    const int ks = t & 255;          // k-slice
    const int k8 = 8 * ks;
    const int co = ks >> 2;
    const int j4 = ks & 3;
    const int bh = t >> 8;           // 0/1: local batch pair
    const int bg0 = quarter * 4 + 2 * bh;

    {   // stage act (sum of two for TWOACT)
        int br = t >> 7, e0 = (t & 127) * 16;
#pragma unroll
        for (int r = 0; r < 4; ++r) {
            float4 u = *(const float4*)&act1[(size_t)(quarter * 4 + br) * KK + e0 + 4 * r];
            if constexpr (TWOACT) {
                float4 u2 = *(const float4*)&act2[(size_t)(quarter * 4 + br) * KK + e0 + 4 * r];
                u.x += u2.x; u.y += u2.y; u.z += u2.z; u.w += u2.w;
            }
            *(float4*)&actb[br][e0 + 4 * r] = u;
        }
    }
    __syncthreads();

    float4 acc[4];
#pragma unroll
    for (int i = 0; i < 4; ++i) acc[i] = make_float4(0.f, 0.f, 0.f, 0.f);

    uint4 vA[2], vB[2];
#pragma unroll
    for (int lb = 0; lb < 2; ++lb)
        vA[lb] = *(const uint4*)&votes[((size_t)gid * BS + bg0 + lb) * (KK / 2) + 4 * ks];

    RILBODY(0, vA, vB)
    RILBODY(1, vB, vA)
    RILBODY(2, vA, vB)
    RILBODY(3, vB, vA)
    RILBODY(4, vA, vB)
    RILBODY(5, vB, vA)
    RILBODY(6, vA, vB)
    RILBODY(7, vB, vA)

#pragma unroll
    for (int lb = 0; lb < 2; ++lb) {
        float* pp = &partials[((size_t)gid * BS + bg0 + lb) * KK + k8];
        *(float4*)pp = acc[2 * lb];
        *(float4*)(pp + 4) = acc[2 * lb + 1];
    }
}

// 256 blocks x 128 threads; 4-way split over G + LDS combine
template <int G>
__global__ __launch_bounds__(128) void reduce_squash(
    const float* __restrict__ partials,   // [G][BS][KK]
    const float* __restrict__ bias,
    float* __restrict__ act_out, float scale)
{
    __shared__ float4 sred[4][32];
    const int t = threadIdx.x;
    const int blk = blockIdx.x;
    const int lane = t & 31;
    const int gp = t >> 5;
    const int o4 = blk * 128 + lane * 4;
    const int b = o4 >> 11;
    const int kk = o4 & (KK - 1);
    const float* p = partials + (size_t)b * KK + kk;
    const size_t stride = (size_t)BS * KK;

    float4 s = make_float4(0.f, 0.f, 0.f, 0.f);
#pragma unroll 4
    for (int g = gp * (G / 4); g < gp * (G / 4) + (G / 4); ++g) {
        float4 v = *(const float4*)(p + (size_t)g * stride);
        s.x += v.x; s.y += v.y; s.z += v.z; s.w += v.w;
    }
    sred[gp][lane] = s;
    __syncthreads();

    if (t < 32) {
        float4 v0 = sred[0][t], v1 = sred[1][t], v2 = sred[2][t], v3 = sred[3][t];
        float4 v;
        v.x = (v0.x + v1.x) + (v2.x + v3.x);
        v.y = (v0.y + v1.y) + (v2.y + v3.y);
        v.z = (v0.z + v1.z) + (v2.z + v3.z);
        v.w = (v0.w + v1.w) + (v2.w + v3.w);
        const int ot = blk * 128 + t * 4;
        float4 bb = *(const float4*)&bias[ot & (KK - 1)];
        v.x = v.x * scale + bb.x;
        v.y = v.y * scale + bb.y;
        v.z = v.z * scale + bb.z;
        v.w = v.w * scale + bb.w;
        float n2 = v.x * v.x + v.y * v.y + v.z * v.z + v.w * v.w;
#pragma unroll
        for (int m = 1; m < 8; m <<= 1) n2 += __shfl_xor(n2, m, 8);
        float norm = sqrtf(n2);
        float sc = norm / (1.f + n2);
        float4 o = make_float4(v.x * sc, v.y * sc, v.z * sc, v.w * sc);
        *(float4*)&act_out[ot] = o;
    }
}

extern "C" void kernel_launch(void* const* d_in, const int* in_sizes, int n_in,
                              void* d_out, int out_size, void* d_ws, size_t ws_size,
                              hipStream_t stream) {
    const float* x = (const float*)d_in[0];
    const float* w = (const float*)d_in[1];
    const float* bias = (const float*)d_in[2];
    float* out = (float*)d_out;

    char* p = (char*)d_ws;
    unsigned* votes = (unsigned*)p; p += (size_t)CI * BS * KK * 2;   // 134 MB (bf16)
    float* partials = (float*)p;    p += (size_t)NGRP * BS * KK * 4; // 33.5 MB
    float* part1 = (float*)p;       p += (size_t)32 * BS * KK * 4;   // 4 MB
    float* act1 = (float*)p;        p += (size_t)BS * KK * 4;
    float* act2 = (float*)p;

    votes_kernel<<<2 * NGRP, 512, 0, stream>>>(x, w, votes);
    vote_sum<<<512, 256, 0, stream>>>(votes, part1);
    reduce_squash<32><<<256, 128, 0, stream>>>(part1, bias, act1, 1.0f / (float)CO);
    route_kernel<false><<<4 * NGRP, 512, 0, stream>>>(votes, act1, nullptr, partials);
    reduce_squash<256><<<256, 128, 0, stream>>>(partials, bias, act2, 1.0f);
    route_kernel<true><<<4 * NGRP, 512, 0, stream>>>(votes, act1, act2, partials);
    reduce_squash<256><<<256, 128, 0, stream>>>(partials, bias, out, 1.0f);
}

// Round 15
// 191.435 us; speedup vs baseline: 3.7198x; 3.7198x over previous
//
#include <hip/hip_runtime.h>

#define BS 16
#define CI 2048
#define NI 16
#define CO 64
#define NO 32
#define KK 2048   // CO*NO
#define NGRP 256  // i-groups

__device__ __forceinline__ void load_lds16(const float* g, float* l) {
    __builtin_amdgcn_global_load_lds(
        (const __attribute__((address_space(1))) void*)g,
        (__attribute__((address_space(3))) void*)l, 16, 0, 0);
}

#define WAITVM12 asm volatile("s_waitcnt vmcnt(12)" ::: "memory")
#define WAITVM4  asm volatile("s_waitcnt vmcnt(4)" ::: "memory")
#define WAITVM0  asm volatile("s_waitcnt vmcnt(0)" ::: "memory")
#define WAITLGKM asm volatile("s_waitcnt lgkmcnt(0)" ::: "memory")
#define BAR __builtin_amdgcn_s_barrier
#define MEMFENCE asm volatile("" ::: "memory")

__device__ __forceinline__ unsigned bf16rne(float f) {
    unsigned u = __float_as_uint(f);
    return (u + 0x7fffu + ((u >> 16) & 1u)) >> 16;
}
__device__ __forceinline__ unsigned pack2(float lo, float hi) {
    return bf16rne(lo) | (bf16rne(hi) << 16);
}
__device__ __forceinline__ float bflo(unsigned u) { return __uint_as_float(u << 16); }
__device__ __forceinline__ float bfhi(unsigned u) { return __uint_as_float(u & 0xffff0000u); }

// ---------------- pass 0: weights -> votes(bf16) + uniform-route sums ------
// REVERTED to the r12/r13-proven version: 512 thr, lb(512,2) -> 128 VGPR
// (the empirical sweet spot: acc[8]+v[8]=64 regs live, minimal spill),
// 512 blocks (sibling pairs share weights via same-XCD L2), self-sliced
// global_load_lds staging, counted vmcnt ledger incl. the 8 vote stores.
// r14's (512,8) gave 32 VGPR -> catastrophic spill. Do not re-attempt.
__global__ __launch_bounds__(512, 2) void votes_kernel(
    const float* __restrict__ x,      // [BS][CI][NI]
    const float* __restrict__ w,      // [CI][NI][KK]
    unsigned* __restrict__ votes,     // [CI][BS][KK/2] u32 = 2 bf16
    float* __restrict__ partials)     // [NGRP][BS][KK]
{
    __shared__ float wbuf[2][4 * KK]; // 64 KB: double-buffered 4-row quarters
    __shared__ float xb[8][8][NI];    // 4 KB

    const int t = threadIdx.x;
    const int phys = blockIdx.x;
    const int xcd = phys & 7;
    const int slot = phys >> 3;
    const int pairid = xcd * 32 + (slot >> 1);
    const int half = slot & 1;
    const int k4 = 4 * t;

    {
        int il = t >> 6, b = (t >> 3) & 7, n0 = (t & 7) * 2;
        int i = pairid + il * NGRP;
        *(float2*)&xb[il][b][n0] =
            *(const float2*)&x[((size_t)(half * 8 + b) * CI + i) * NI + n0];
    }
    __syncthreads();  // x visible; counters drained: exact ledger starts

    float4 acc[8];
#pragma unroll
    for (int b = 0; b < 8; ++b) acc[b] = make_float4(0.f, 0.f, 0.f, 0.f);

    auto issue = [&](int s) {   // quarter s: capsule s>>2, ni rows 4(s&3)..+3
        int ilp = s >> 2, qp = s & 3;
        const float* gb = w + ((size_t)(pairid + ilp * NGRP) * NI + qp * 4) * KK + k4;
        float* lb = wbuf[s & 1] + k4;
#pragma unroll
        for (int r = 0; r < 4; ++r)
            load_lds16(gb + (size_t)r * KK, lb + r * KK);
    };

    auto computequarter = [&](int il, int q, float4(&dst)[8]) {
#pragma unroll
        for (int rg = 0; rg < 2; ++rg) {
            float4 wA = *(const float4*)&wbuf[q & 1][(2 * rg) * KK + k4];
            float4 wB = *(const float4*)&wbuf[q & 1][(2 * rg + 1) * KK + k4];
#pragma unroll
            for (int b = 0; b < 8; ++b) {
                float2 xv = *(const float2*)&xb[il][b][q * 4 + 2 * rg];
                dst[b].x = fmaf(xv.x, wA.x, dst[b].x);
                dst[b].y = fmaf(xv.x, wA.y, dst[b].y);
                dst[b].z = fmaf(xv.x, wA.z, dst[b].z);
                dst[b].w = fmaf(xv.x, wA.w, dst[b].w);
                dst[b].x = fmaf(xv.y, wB.x, dst[b].x);
                dst[b].y = fmaf(xv.y, wB.y, dst[b].y);
                dst[b].z = fmaf(xv.y, wB.z, dst[b].z);
                dst[b].w = fmaf(xv.y, wB.w, dst[b].w);
            }
        }
    };

    issue(0); issue(1);

#pragma unroll 1
    for (int il = 0; il < 8; ++il) {
        float4 v[8];
#pragma unroll
        for (int b = 0; b < 8; ++b) v[b] = make_float4(0.f, 0.f, 0.f, 0.f);

#pragma unroll
        for (int q = 0; q < 4; ++q) {
            if (q < 2) { if (il > 0) { WAITVM12; } else { WAITVM4; } }
            else if (q == 3) { if (il == 7) { WAITVM0; } else { WAITVM4; } }
            else { WAITVM4; }
            computequarter(il, q, v);
            WAITLGKM;
            if (il < 7 || q < 2) issue(il * 4 + q + 2);
        }

        const size_t vbase = ((size_t)(pairid + il * NGRP) * BS + half * 8) * (KK / 2) + 2 * t;
#pragma unroll
        for (int b = 0; b < 8; ++b) {
            acc[b].x += v[b].x; acc[b].y += v[b].y;
            acc[b].z += v[b].z; acc[b].w += v[b].w;
            uint2 pk;
            pk.x = pack2(v[b].x, v[b].y);
            pk.y = pack2(v[b].z, v[b].w);
            *(uint2*)&votes[vbase + (size_t)b * (KK / 2)] = pk;
        }
        MEMFENCE;
    }

#pragma unroll
    for (int b = 0; b < 8; ++b)
        *(float4*)&partials[((size_t)pairid * BS + half * 8 + b) * KK + k4] = acc[b];
}

// ---------------- routing from bf16 votes (r13 structure, no logits) -------
// Linearity: iter-3 logits = v.act1 + v.act2 = v.(act1+act2), so route2 is
// route1 with actb = act1+act2. Zero logits traffic, no lg registers.
#define RILBODY(IL, VC, VN)                                                    \
  {                                                                            \
    const int buf = (IL) & 1;                                                  \
    if ((IL) < 7) {                                                            \
      _Pragma("unroll")                                                        \
      for (int lb = 0; lb < 2; ++lb)                                           \
        VN[lb] = *(const uint4*)&votes[((size_t)(gid + ((IL) + 1) * NGRP) * BS \
                                        + bg0 + lb) * (KK / 2) + 4 * ks];      \
    }                                                                          \
    float dv[2];                                                               \
    _Pragma("unroll")                                                          \
    for (int lb = 0; lb < 2; ++lb) {                                           \
      float4 a0 = *(const float4*)&actb[2 * bh + lb][k8];                      \
      float4 a1 = *(const float4*)&actb[2 * bh + lb][k8 + 4];                  \
      float d = bflo(VC[lb].x) * a0.x + bfhi(VC[lb].x) * a0.y                  \
              + bflo(VC[lb].y) * a0.z + bfhi(VC[lb].y) * a0.w                  \
              + bflo(VC[lb].z) * a1.x + bfhi(VC[lb].z) * a1.y                  \
              + bflo(VC[lb].w) * a1.z + bfhi(VC[lb].w) * a1.w;                 \
      d += __shfl_xor(d, 1, 4);                                                \
      d += __shfl_xor(d, 2, 4);                                                \
      dv[lb] = d;                                                              \
    }                                                                          \
    if (j4 == 0) sm[buf][(2 * bh) * 65 + co] = dv[0];                          \
    if (j4 == 1) sm[buf][(2 * bh + 1) * 65 + co] = dv[1];                      \
    WAITLGKM; BAR();                                                           \
    if (t < 256) {                                                             \
      float l0 = sm[buf][(t >> 6) * 65 + (t & 63)];                            \
      float mx = l0;                                                           \
      mx = fmaxf(mx, __shfl_xor(mx, 1, 64));                                   \
      mx = fmaxf(mx, __shfl_xor(mx, 2, 64));                                   \
      mx = fmaxf(mx, __shfl_xor(mx, 4, 64));                                   \
      mx = fmaxf(mx, __shfl_xor(mx, 8, 64));                                   \
      mx = fmaxf(mx, __shfl_xor(mx, 16, 64));                                  \
      mx = fmaxf(mx, __shfl_xor(mx, 32, 64));                                  \
      float e = __expf(l0 - mx);                                               \
      float ssum = e;                                                          \
      ssum += __shfl_xor(ssum, 1, 64);                                         \
      ssum += __shfl_xor(ssum, 2, 64);                                         \
      ssum += __shfl_xor(ssum, 4, 64);                                         \
      ssum += __shfl_xor(ssum, 8, 64);                                         \
      ssum += __shfl_xor(ssum, 16, 64);                                        \
      ssum += __shfl_xor(ssum, 32, 64);                                        \
      sm[buf][(t >> 6) * 65 + (t & 63)] = e / ssum;                            \
      WAITLGKM;                                                                \
    }                                                                          \
    BAR();                                                                     \
    _Pragma("unroll")                                                          \
    for (int lb = 0; lb < 2; ++lb) {                                           \
      float r = sm[buf][(2 * bh + lb) * 65 + co];                              \
      acc[2 * lb + 0].x = fmaf(r, bflo(VC[lb].x), acc[2 * lb + 0].x);          \
      acc[2 * lb + 0].y = fmaf(r, bfhi(VC[lb].x), acc[2 * lb + 0].y);          \
      acc[2 * lb + 0].z = fmaf(r, bflo(VC[lb].y), acc[2 * lb + 0].z);          \
      acc[2 * lb + 0].w = fmaf(r, bfhi(VC[lb].y), acc[2 * lb + 0].w);          \
      acc[2 * lb + 1].x = fmaf(r, bflo(VC[lb].z), acc[2 * lb + 1].x);          \
      acc[2 * lb + 1].y = fmaf(r, bfhi(VC[lb].z), acc[2 * lb + 1].y);          \
      acc[2 * lb + 1].z = fmaf(r, bflo(VC[lb].w), acc[2 * lb + 1].z);          \
      acc[2 * lb + 1].w = fmaf(r, bfhi(VC[lb].w), acc[2 * lb + 1].w);          \
    }                                                                          \
  }

template <bool TWOACT>
__global__ __launch_bounds__(512, 2) void route_kernel(
    const unsigned* __restrict__ votes,   // [CI][BS][KK/2]
    const float* __restrict__ act1,       // [BS][KK]
    const float* __restrict__ act2,       // [BS][KK] (TWOACT only)
    float* __restrict__ partials)         // [NGRP][BS][KK]
{
    __shared__ float actb[4][KK];   // 32 KB (act1 or act1+act2)
    __shared__ float sm[2][4 * 65]; // 2 KB, double-buffered per il

    const int t = threadIdx.x;       // 0..511
    const int phys = blockIdx.x;     // 0..1023
    const int xcd = phys & 7;
    const int slot = phys >> 3;      // 0..127
    const int gid = xcd * 32 + (slot >> 2);  // 0..255
    const int quarter = slot & 3;    // batches quarter*4 .. +3

    const int ks = t & 255;          // k-slice
    const int k8 = 8 * ks;
    const int co = ks >> 2;
    const int j4 = ks & 3;
    const int bh = t >> 8;           // 0/1: local batch pair
    const int bg0 = quarter * 4 + 2 * bh;

    {   // stage act (sum of two for TWOACT)
        int br = t >> 7, e0 = (t & 127) * 16;
#pragma unroll
        for (int r = 0; r < 4; ++r) {
            float4 u = *(const float4*)&act1[(size_t)(quarter * 4 + br) * KK + e0 + 4 * r];
            if constexpr (TWOACT) {
                float4 u2 = *(const float4*)&act2[(size_t)(quarter * 4 + br) * KK + e0 + 4 * r];
                u.x += u2.x; u.y += u2.y; u.z += u2.z; u.w += u2.w;
            }
            *(float4*)&actb[br][e0 + 4 * r] = u;
        }
    }
    __syncthreads();

    float4 acc[4];
#pragma unroll
    for (int i = 0; i < 4; ++i) acc[i] = make_float4(0.f, 0.f, 0.f, 0.f);

    uint4 vA[2], vB[2];
#pragma unroll
    for (int lb = 0; lb < 2; ++lb)
        vA[lb] = *(const uint4*)&votes[((size_t)gid * BS + bg0 + lb) * (KK / 2) + 4 * ks];

    RILBODY(0, vA, vB)
    RILBODY(1, vB, vA)
    RILBODY(2, vA, vB)
    RILBODY(3, vB, vA)
    RILBODY(4, vA, vB)
    RILBODY(5, vB, vA)
    RILBODY(6, vA, vB)
    RILBODY(7, vB, vA)

#pragma unroll
    for (int lb = 0; lb < 2; ++lb) {
        float* pp = &partials[((size_t)gid * BS + bg0 + lb) * KK + k8];
        *(float4*)pp = acc[2 * lb];
        *(float4*)(pp + 4) = acc[2 * lb + 1];
    }
}

// 256 blocks x 128 threads; 4-way split over NGRP + LDS combine
__global__ __launch_bounds__(128) void reduce_squash(
    const float* __restrict__ partials,   // [NGRP][BS][KK]
    const float* __restrict__ bias,
    float* __restrict__ act_out, float scale)
{
    __shared__ float4 sred[4][32];
    const int t = threadIdx.x;
    const int blk = blockIdx.x;
    const int lane = t & 31;
    const int gp = t >> 5;
    const int o4 = blk * 128 + lane * 4;
    const int b = o4 >> 11;
    const int kk = o4 & (KK - 1);
    const float* p = partials + (size_t)b * KK + kk;
    const size_t stride = (size_t)BS * KK;

    float4 s = make_float4(0.f, 0.f, 0.f, 0.f);
#pragma unroll 4
    for (int g = gp * 64; g < gp * 64 + 64; ++g) {
        float4 v = *(const float4*)(p + (size_t)g * stride);
        s.x += v.x; s.y += v.y; s.z += v.z; s.w += v.w;
    }
    sred[gp][lane] = s;
    __syncthreads();

    if (t < 32) {
        float4 v0 = sred[0][t], v1 = sred[1][t], v2 = sred[2][t], v3 = sred[3][t];
        float4 v;
        v.x = (v0.x + v1.x) + (v2.x + v3.x);
        v.y = (v0.y + v1.y) + (v2.y + v3.y);
        v.z = (v0.z + v1.z) + (v2.z + v3.z);
        v.w = (v0.w + v1.w) + (v2.w + v3.w);
        const int ot = blk * 128 + t * 4;
        float4 bb = *(const float4*)&bias[ot & (KK - 1)];
        v.x = v.x * scale + bb.x;
        v.y = v.y * scale + bb.y;
        v.z = v.z * scale + bb.z;
        v.w = v.w * scale + bb.w;
        float n2 = v.x * v.x + v.y * v.y + v.z * v.z + v.w * v.w;
#pragma unroll
        for (int m = 1; m < 8; m <<= 1) n2 += __shfl_xor(n2, m, 8);
        float norm = sqrtf(n2);
        float sc = norm / (1.f + n2);
        float4 o = make_float4(v.x * sc, v.y * sc, v.z * sc, v.w * sc);
        *(float4*)&act_out[ot] = o;
    }
}

extern "C" void kernel_launch(void* const* d_in, const int* in_sizes, int n_in,
                              void* d_out, int out_size, void* d_ws, size_t ws_size,
                              hipStream_t stream) {
    const float* x = (const float*)d_in[0];
    const float* w = (const float*)d_in[1];
    const float* bias = (const float*)d_in[2];
    float* out = (float*)d_out;

    char* p = (char*)d_ws;
    unsigned* votes = (unsigned*)p; p += (size_t)CI * BS * KK * 2;   // 134 MB (bf16)
    float* partials = (float*)p;    p += (size_t)NGRP * BS * KK * 4; // 33.5 MB
    float* act1 = (float*)p;        p += (size_t)BS * KK * 4;
    float* act2 = (float*)p;

    votes_kernel<<<2 * NGRP, 512, 0, stream>>>(x, w, votes, partials);
    reduce_squash<<<256, 128, 0, stream>>>(partials, bias, act1, 1.0f / (float)CO);
    route_kernel<false><<<4 * NGRP, 512, 0, stream>>>(votes, act1, nullptr, partials);
    reduce_squash<<<256, 128, 0, stream>>>(partials, bias, act2, 1.0f);
    route_kernel<true><<<4 * NGRP, 512, 0, stream>>>(votes, act1, act2, partials);
    reduce_squash<<<256, 128, 0, stream>>>(partials, bias, out, 1.0f);
}